// Round 10
// baseline (30108.505 us; speedup 1.0000x reference)
//
#include <hip/hip_runtime.h>

#define NHID 512
#define NXW  128
#define TLEN 16384
#define STEPS (TLEN - NXW)      // 16256
#define G    32                 // persistent workgroups
#define B    512                // 8 waves per WG
#define RPW  16                 // hidden rows owned per WG
#define RSLOTS 8                // sync ring depth (32 KB -> IC/L2-hot)

#define FOR4(M)  M(0) M(1) M(2) M(3)
#define FOR16(M) M(0) M(1) M(2) M(3) M(4) M(5) M(6) M(7) \
                 M(8) M(9) M(10) M(11) M(12) M(13) M(14) M(15)

__device__ __forceinline__ float sigmoid_f(float v) { return 1.f / (1.f + __expf(-v)); }
__device__ __forceinline__ float tanh_f(float v)    { return 1.f - 2.f / (1.f + __expf(2.f * v)); }

// ---------------------------------------------------------------------------
// R6 core + PARALLEL per-wave tail (wave 0 serialization removed).
// WG g owns rows [g*16, g*16+16).
// FMA phase (unchanged): lane l computes output l (gate l>>4, row g*16+(l&15))
//   over k-slice [w*64, w*64+64); h staged in h_buf[w] (uniform-address
//   broadcast reads).
// Tail phase (new): wave w owns WG-rows {2w, 2w+1}. Lane l -> (d=l>>5 row sel,
//   tq=(l>>3)&3 gate, ts=l&7 slice). Reads partials[ts][tq*16+2w+d] (stride-65
//   pad -> conflict-free), 3-stage shfl_xor reduce over ts, activation,
//   4 shfl gathers for f,i,o,g, c replicated per 32-lane row-group,
//   lanes 0/32 publish {tag,h} to the ring. All 8 waves tail in parallel.
// ---------------------------------------------------------------------------
__launch_bounds__(B, 2)
__global__ void lstm_persistent(
    const float* x,
    const float* Wf, const float* Uf, const float* bf,
    const float* Wi, const float* Ui, const float* bi,
    const float* Wo, const float* Uo, const float* bo,
    const float* Wc, const float* Uc, const float* bc,
    unsigned long long* ring,     // [RSLOTS][NHID] packed {tag,h}
    float* h_hist)                // [STEPS][NHID] for mu only
{
    __shared__ float x_win[256];                    // x ring: refill every 128 steps
    __shared__ __align__(16) float h_buf[8][64];    // per-wave h-slice staging
    __shared__ float partials[2][8][65];            // [buf][slice][out+pad]

    const int tid = threadIdx.x;
    const int g   = blockIdx.x;
    const int w   = tid >> 6;            // wave = k-slice 0..7
    const int l   = tid & 63;            // FMA: output 0..63
    const int q   = l >> 4;              // FMA: gate 0=f 1=i 2=o 3=c
    const int row = g * RPW + (l & 15);  // FMA: global row of output l

    const float* Utab[4] = {Uf, Ui, Uo, Uc};
    const float* Wtab[4] = {Wf, Wi, Wo, Wc};
    const float* Btab[4] = {bf, bi, bo, bc};

    // load + pin weights: 64 U floats + 16 W floats per thread (R6-proven)
    const float4* Up = (const float4*)(Utab[q] + (size_t)row * NHID + w * 64);
    #define DECLU(i) float4 u##i = Up[i];
    FOR16(DECLU)
    const float4* Wp = (const float4*)(Wtab[q] + row * NXW + w * 16);
    #define DECLW(i) float4 wv##i = Wp[i];
    FOR4(DECLW)
    #define PIN(r) asm volatile("" : "+v"(r.x), "+v"(r.y), "+v"(r.z), "+v"(r.w));
    #define PINU(i) PIN(u##i)
    FOR16(PINU)
    #define PINW(i) PIN(wv##i)
    FOR4(PINW)

    // tail-phase identities: wave w owns WG-rows 2w (lanes 0-31), 2w+1 (32-63)
    const int td   = l >> 5;                 // row select within wave
    const int tq   = (l >> 3) & 3;           // gate
    const int ts   = l & 7;                  // slice index to reduce over
    const int tout = tq * 16 + 2 * w + td;   // out index in partials
    const int trow = g * RPW + 2 * w + td;   // global row
    const float tbias = Btab[tq][trow];
    float c_prev = 0.f;                      // c for trow, replicated in 32 lanes

    // mu-history writer: WG g stores its own 16 rows from its polled values
    const bool hist_writer = (w == (g >> 2)) && ((l >> 4) == (g & 3));

    h_buf[w][l] = 0.f;                   // h[-1] = 0 (own wave reads only)

    for (int t = 0; t < STEPS; ++t) {
        if ((t & 127) == 0) {            // x window refill (covers x[t..t+255])
            __syncthreads();
            if (tid < 256) {
                int gi = t + tid;
                x_win[tid] = (gi < TLEN) ? x[gi] : 0.f;
            }
            __syncthreads();
        }

        // x-projection partial (independent of h -> overlaps producer latency)
        float xacc = 0.f;
        {
            const int xb = (t & 127) + w * 16;
            #define XF(i) xacc += wv##i.x * x_win[xb + 4*i]     \
                                + wv##i.y * x_win[xb + 4*i + 1] \
                                + wv##i.z * x_win[xb + 4*i + 2] \
                                + wv##i.w * x_win[xb + 4*i + 3];
            FOR4(XF)
        }

        // poll own 8B ring word of h[t-1]: hot line, tag-validated (R6 poll)
        float hval = 0.f;
        if (t > 0) {
            const unsigned long long* src =
                ring + ((size_t)((t - 1) & (RSLOTS - 1)) << 9) + (w * 64 + l);
            const unsigned want = (unsigned)(t - 1);
            unsigned long long vv; int guard = 0;
            do {
                vv = __hip_atomic_load(src, __ATOMIC_RELAXED, __HIP_MEMORY_SCOPE_AGENT);
            } while ((unsigned)(vv >> 32) != want && ++guard < (1 << 20));
            hval = __uint_as_float((unsigned)vv);
            h_buf[w][l] = hval;
        }

        // U @ h slice: 64 FMA vs wave-uniform LDS broadcast reads
        float acc = xacc;
        const float4* hb4 = (const float4*)h_buf[w];
        #define UF(i) { float4 hv = hb4[i];                       \
                        acc += u##i.x * hv.x + u##i.y * hv.y      \
                             + u##i.z * hv.z + u##i.w * hv.w; }
        FOR16(UF)
        partials[t & 1][w][l] = acc;

        __syncthreads();                 // the ONE per-step barrier

        // ---- parallel tail: every wave finishes its own 2 rows ----
        float sum = partials[t & 1][ts][tout];
        sum += __shfl_xor(sum, 1, 64);
        sum += __shfl_xor(sum, 2, 64);
        sum += __shfl_xor(sum, 4, 64);
        sum += tbias;
        float a = (tq < 3) ? sigmoid_f(sum) : tanh_f(sum);
        const int base = l & 0x27;       // keep d (bit5) + s (bits 0-2)
        float fA = __shfl(a, base,        64);
        float iA = __shfl(a, base | 0x08, 64);
        float oA = __shfl(a, base | 0x10, 64);
        float gA = __shfl(a, base | 0x18, 64);
        float c  = fA * c_prev + iA * gA;
        c_prev = c;
        float h = oA * tanh_f(c);
        if ((l & 31) == 0) {
            unsigned long long pv =
                ((unsigned long long)(unsigned)t << 32)
                | (unsigned long long)__float_as_uint(h);
            __hip_atomic_store(
                ring + ((size_t)(t & (RSLOTS - 1)) << 9) + trow, pv,
                __ATOMIC_RELAXED, __HIP_MEMORY_SCOPE_AGENT);
            if (t == STEPS - 1)          // last h is never polled: store direct
                h_hist[(size_t)t * NHID + trow] = h;
        }

        // mu-history store for step t-1 (off the critical path, sinkable)
        if (t > 0 && hist_writer)
            h_hist[(size_t)(t - 1) * NHID + w * 64 + l] = hval;
    }
}

// ---------------------------------------------------------------------------
// epilogue: mu[t] = Ahy . h_hist[t] + by   (one wave per t)
// ---------------------------------------------------------------------------
__global__ void mu_kernel(const float* __restrict__ h_hist,
                          const float* __restrict__ Ahy,
                          const float* __restrict__ by,
                          float* __restrict__ outp, int steps)
{
    int wave = threadIdx.x >> 6;
    int lane = threadIdx.x & 63;
    int t = blockIdx.x * 4 + wave;
    if (t >= steps) return;
    const float* h = h_hist + (size_t)t * NHID;
    float p = 0.f;
    #pragma unroll
    for (int e = 0; e < 8; e++)
        p += Ahy[e * 64 + lane] * h[e * 64 + lane];
    #pragma unroll
    for (int off = 32; off; off >>= 1) p += __shfl_down(p, off, 64);
    if (lane == 0) outp[t] = p + by[0];
}

// ---------------------------------------------------------------------------
extern "C" void kernel_launch(void* const* d_in, const int* in_sizes, int n_in,
                              void* d_out, int out_size, void* d_ws, size_t ws_size,
                              hipStream_t stream)
{
    const float* x  = (const float*)d_in[0];
    const float* Wf = (const float*)d_in[1];
    const float* Uf = (const float*)d_in[2];
    const float* bf = (const float*)d_in[3];
    const float* Wi = (const float*)d_in[4];
    const float* Ui = (const float*)d_in[5];
    const float* bi = (const float*)d_in[6];
    const float* Wo = (const float*)d_in[7];
    const float* Uo = (const float*)d_in[8];
    const float* bo = (const float*)d_in[9];
    const float* Wc = (const float*)d_in[10];
    const float* Uc = (const float*)d_in[11];
    const float* bc = (const float*)d_in[12];
    const float* Ahy = (const float*)d_in[13];
    const float* by  = (const float*)d_in[14];

    unsigned long long* ring = (unsigned long long*)d_ws;        // 32 KB
    float* h_hist = (float*)((char*)d_ws + RSLOTS * NHID * 8);   // ~33.3 MB

    lstm_persistent<<<G, B, 0, stream>>>(x, Wf, Uf, bf, Wi, Ui, bi,
                                         Wo, Uo, bo, Wc, Uc, bc, ring, h_hist);
    int muBlocks = (STEPS + 3) / 4;
    mu_kernel<<<muBlocks, 256, 0, stream>>>(h_hist, Ahy, by, (float*)d_out, STEPS);
}